// Round 1
// baseline (93.679 us; speedup 1.0000x reference)
//
#include <hip/hip_runtime.h>

#define NX 4096
#define NY 2048
#define EPS 1e-8f

__device__ __forceinline__ float weno5(float qm2, float qm1, float q0, float qp1, float qp2) {
    const float f1 = (1.0f/3.0f)*qm2 - (7.0f/6.0f)*qm1 + (11.0f/6.0f)*q0;
    const float f2 = -(1.0f/6.0f)*qm1 + (5.0f/6.0f)*q0 + (1.0f/3.0f)*qp1;
    const float f3 = (1.0f/3.0f)*q0 + (5.0f/6.0f)*qp1 - (1.0f/6.0f)*qp2;
    const float k1 = 13.0f/12.0f, k2 = 0.25f;
    float d1 = qm2 - 2.0f*qm1 + q0;
    float e1 = qm2 - 4.0f*qm1 + 3.0f*q0;
    float b1 = k1*d1*d1 + k2*e1*e1;
    float d2 = qm1 - 2.0f*q0 + qp1;
    float e2 = qm1 - qp1;
    float b2 = k1*d2*d2 + k2*e2*e2;
    float d3 = q0 - 2.0f*qp1 + qp2;
    float e3 = 3.0f*q0 - 4.0f*qp1 + qp2;
    float b3 = k1*d3*d3 + k2*e3*e3;
    float t1 = b1 + EPS, t2 = b2 + EPS, t3 = b3 + EPS;
    float w1 = 0.1f/(t1*t1);
    float w2 = 0.6f/(t2*t2);
    float w3 = 0.3f/(t3*t3);
    return (w1*f1 + w2*f2 + w3*f3) / (w1 + w2 + w3);
}

// Upwind face flux: face between cell i and i+1; stencil values hm2..hp3 are
// h at cells i-2 .. i+3. vel is u (or v) at cell i.
__device__ __forceinline__ float face_flux(float vel, float hm2, float hm1, float h0,
                                           float hp1, float hp2, float hp3) {
    bool pos = (vel >= 0.0f);
    float a = pos ? hm2 : hp3;
    float b = pos ? hm1 : hp2;
    float c = pos ? h0  : hp1;
    float d = pos ? hp1 : h0;
    float e = pos ? hp2 : hm1;
    return vel * weno5(a, b, c, d, e);
}

__device__ __forceinline__ int clampi(int i, int lo, int hi) {
    return i < lo ? lo : (i > hi ? hi : i);
}

__global__ __launch_bounds__(256) void adv_kernel(const float* __restrict__ h,
                                                  const float* __restrict__ u,
                                                  const float* __restrict__ v,
                                                  float* __restrict__ out) {
    int x = blockIdx.x * 64 + (threadIdx.x & 63);
    int y = blockIdx.y * 4 + (threadIdx.x >> 6);

    bool interior = (x >= 2) && (x < NX - 2) && (y >= 2) && (y < NY - 2);
    if (!interior) {
        out[y * NX + x] = 0.0f;
        return;
    }

    // ---- x-direction: faces at i = x-1 and i = x. Need h[y][x-3 .. x+3].
    float hx[7];
#pragma unroll
    for (int k = 0; k < 7; ++k) {
        int xi = clampi(x - 3 + k, 0, NX - 1);
        hx[k] = h[y * NX + xi];
    }
    float u_m1 = u[y * NX + (x - 1)];
    float u_0  = u[y * NX + x];
    // face x-1: cells (x-1-2 .. x-1+3) = hx[0..5]
    float fe_m1 = face_flux(u_m1, hx[0], hx[1], hx[2], hx[3], hx[4], hx[5]);
    // face x:   cells (x-2 .. x+3)   = hx[1..6]
    float fe_0  = face_flux(u_0,  hx[1], hx[2], hx[3], hx[4], hx[5], hx[6]);

    // ---- y-direction: faces at j = y-1 and j = y. Need h[y-3 .. y+3][x].
    float hy[7];
#pragma unroll
    for (int k = 0; k < 7; ++k) {
        int yi = clampi(y - 3 + k, 0, NY - 1);
        hy[k] = h[yi * NX + x];
    }
    float v_m1 = v[(y - 1) * NX + x];
    float v_0  = v[y * NX + x];
    float fn_m1 = face_flux(v_m1, hy[0], hy[1], hy[2], hy[3], hy[4], hy[5]);
    float fn_0  = face_flux(v_0,  hy[1], hy[2], hy[3], hy[4], hy[5], hy[6]);

    float div = (fe_0 - fe_m1) * (1.0f / 1000.0f) + (fn_0 - fn_m1) * (1.0f / 1000.0f);
    out[y * NX + x] = -div;
}

extern "C" void kernel_launch(void* const* d_in, const int* in_sizes, int n_in,
                              void* d_out, int out_size, void* d_ws, size_t ws_size,
                              hipStream_t stream) {
    const float* h = (const float*)d_in[0];
    const float* u = (const float*)d_in[1];
    const float* v = (const float*)d_in[2];
    float* out = (float*)d_out;

    dim3 block(256, 1, 1);
    dim3 grid(NX / 64, NY / 4, 1);
    adv_kernel<<<grid, block, 0, stream>>>(h, u, v, out);
}

// Round 2
// 43.356 us; speedup vs baseline: 2.1607x; 2.1607x over previous
//
#include <hip/hip_runtime.h>

#define NX 4096
#define NY 2048
#define EPS 1e-8f
#define ROWS 8      // output rows per thread (vertical strip)
#define CPW 63      // output columns per wave (64 lanes compute 64 faces)
#define INV_D 0.001f

__device__ __forceinline__ int clampi(int i, int lo, int hi) {
    return i < lo ? lo : (i > hi ? hi : i);
}

// One-divide WENO5: weights scaled by (t1*t2*t3)^2 so only a single
// reciprocal is needed. t_i >= EPS=1e-8 -> (t_j*t_k)^2 >= 1e-32, still a
// normal fp32, so no underflow-to-zero in the denominator.
__device__ __forceinline__ float weno5(float qm2, float qm1, float q0, float qp1, float qp2) {
    const float f1 = fmaf(1.0f/3.0f, qm2, fmaf(-7.0f/6.0f, qm1, (11.0f/6.0f)*q0));
    const float f2 = fmaf(-1.0f/6.0f, qm1, fmaf(5.0f/6.0f, q0, (1.0f/3.0f)*qp1));
    const float f3 = fmaf(1.0f/3.0f, q0, fmaf(5.0f/6.0f, qp1, (-1.0f/6.0f)*qp2));
    const float k1 = 13.0f/12.0f, k2 = 0.25f;
    float d1 = qm2 - 2.0f*qm1 + q0;
    float e1 = qm2 - 4.0f*qm1 + 3.0f*q0;
    float d2 = qm1 - 2.0f*q0 + qp1;
    float e2 = qm1 - qp1;
    float d3 = q0 - 2.0f*qp1 + qp2;
    float e3 = 3.0f*q0 - 4.0f*qp1 + qp2;
    float b1 = fmaf(k1, d1*d1, k2*(e1*e1));
    float b2 = fmaf(k1, d2*d2, k2*(e2*e2));
    float b3 = fmaf(k1, d3*d3, k2*(e3*e3));
    float t1 = b1 + EPS, t2 = b2 + EPS, t3 = b3 + EPS;
    float p23 = t2*t3, p13 = t1*t3, p12 = t1*t2;
    float w1 = 0.1f*(p23*p23);
    float w2 = 0.6f*(p13*p13);
    float w3 = 0.3f*(p12*p12);
    float num = fmaf(w1, f1, fmaf(w2, f2, w3*f3));
    float den = (w1 + w2) + w3;
    return num * __builtin_amdgcn_rcpf(den);
}

// Face between cells i and i+1; hm2..hp3 = h at cells i-2 .. i+3; vel = u[i].
__device__ __forceinline__ float face_flux(float vel, float hm2, float hm1, float h0,
                                           float hp1, float hp2, float hp3) {
    bool pos = (vel >= 0.0f);
    float a = pos ? hm2 : hp3;
    float b = pos ? hm1 : hp2;
    float c = pos ? h0  : hp1;
    float d = pos ? hp1 : h0;
    float e = pos ? hp2 : hm1;
    return vel * weno5(a, b, c, d, e);
}

__global__ __launch_bounds__(256) void adv_kernel(const float* __restrict__ h,
                                                  const float* __restrict__ u,
                                                  const float* __restrict__ v,
                                                  float* __restrict__ out) {
    const int lane = threadIdx.x & 63;
    const int wid  = threadIdx.x >> 6;
    const int x0 = blockIdx.x * CPW;       // first output column of this block
    const int xf = x0 - 1 + lane;          // face column this lane computes
    const int xo = x0 + lane;              // output column (lanes 0..62 write)
    const int y0 = (blockIdx.y * 4 + wid) * ROWS;

    // Row-invariant clamped x indices for the fe stencil and velocity.
    int xs0 = clampi(xf - 2, 0, NX - 1);
    int xs1 = clampi(xf - 1, 0, NX - 1);
    int xs2 = clampi(xf,     0, NX - 1);
    int xs3 = clampi(xf + 1, 0, NX - 1);
    int xs4 = clampi(xf + 2, 0, NX - 1);
    int xs5 = clampi(xf + 3, 0, NX - 1);
    const int xc = xo < NX ? xo : NX - 1;  // column for fn/v loads

    // ---- y-direction: 9 faces at rows y0-1 .. y0+7, column xc.
    float w[ROWS + 6];
#pragma unroll
    for (int k = 0; k < ROWS + 6; ++k) {
        int yy = clampi(y0 - 3 + k, 0, NY - 1);
        w[k] = h[(size_t)yy * NX + xc];
    }
    float fn[ROWS + 1];
#pragma unroll
    for (int j = 0; j <= ROWS; ++j) {
        int fy = clampi(y0 - 1 + j, 0, NY - 1);
        float vv = v[(size_t)fy * NX + xc];
        fn[j] = face_flux(vv, w[j], w[j+1], w[j+2], w[j+3], w[j+4], w[j+5]);
    }

    // ---- per row: one x-face per lane, neighbor face via shuffle, combine.
#pragma unroll
    for (int r = 0; r < ROWS; ++r) {
        int y = y0 + r;
        const float* hr = h + (size_t)y * NX;
        float fe = face_flux(u[(size_t)y * NX + xs2],
                             hr[xs0], hr[xs1], hr[xs2], hr[xs3], hr[xs4], hr[xs5]);
        float fe_right = __shfl_down(fe, 1);   // face at column xo (lane+1's face)
        if (lane < CPW && xo < NX) {
            float val = 0.0f;
            if (xo >= 2 && xo < NX - 2 && y >= 2 && y < NY - 2) {
                val = -((fe_right - fe) + (fn[r + 1] - fn[r])) * INV_D;
            }
            out[(size_t)y * NX + xo] = val;
        }
    }
}

extern "C" void kernel_launch(void* const* d_in, const int* in_sizes, int n_in,
                              void* d_out, int out_size, void* d_ws, size_t ws_size,
                              hipStream_t stream) {
    const float* h = (const float*)d_in[0];
    const float* u = (const float*)d_in[1];
    const float* v = (const float*)d_in[2];
    float* out = (float*)d_out;

    dim3 block(256, 1, 1);
    dim3 grid((NX + CPW - 1) / CPW, NY / (4 * ROWS), 1);  // 66 x 64
    adv_kernel<<<grid, block, 0, stream>>>(h, u, v, out);
}